// Round 1
// baseline (1603.759 us; speedup 1.0000x reference)
//
#include <hip/hip_runtime.h>
#include <math.h>

#define BQ   4096
#define FD   512
#define NATT 8192
#define NDB  (BQ + NATT)   // 12288
#define DD   (2 * FD)      // 1024
#define KTOP 32
#define EPSF 1e-7f

// Static device scratch (ws_size is unknown; these are deterministic — fully
// rewritten before every read within one kernel_launch call).
__device__ float g_dbn[(size_t)NDB * DD];         // 48 MB normalized db (rows 0..4095 == normalized queries)
__device__ float g_sims[(size_t)BQ * NDB];        // 201 MB similarity matrix
__device__ int   g_topk[BQ * KTOP];

__device__ __forceinline__ unsigned fkey(float f) {
    unsigned u = __float_as_uint(f);
    return (u & 0x80000000u) ? ~u : (u | 0x80000000u);  // monotonic float->uint
}

// ---------------- 1. L2-normalize db rows (concat re|im, D=1024) -------------
__global__ __launch_bounds__(256) void normalize_kernel(
        const float* __restrict__ x_real, const float* __restrict__ x_imag,
        const float* __restrict__ att_real, const float* __restrict__ att_imag) {
    int row = blockIdx.x;
    int t = threadIdx.x;
    const float *re, *im;
    if (row < BQ) { re = x_real + (size_t)row * FD;        im = x_imag + (size_t)row * FD; }
    else          { re = att_real + (size_t)(row - BQ) * FD; im = att_imag + (size_t)(row - BQ) * FD; }
    float2 vr = *(const float2*)(re + 2 * t);
    float2 vi = *(const float2*)(im + 2 * t);
    float ss = vr.x * vr.x + vr.y * vr.y + vi.x * vi.x + vi.y * vi.y;
#pragma unroll
    for (int o = 32; o > 0; o >>= 1) ss += __shfl_down(ss, o);
    __shared__ float wsum[4];
    __shared__ float s_norm;
    if ((t & 63) == 0) wsum[t >> 6] = ss;
    __syncthreads();
    if (t == 0) s_norm = sqrtf(wsum[0] + wsum[1] + wsum[2] + wsum[3]);
    __syncthreads();
    float nrm = s_norm;
    float* dst = g_dbn + (size_t)row * DD;
    *(float2*)(dst + 2 * t)      = make_float2(vr.x / nrm, vr.y / nrm);
    *(float2*)(dst + FD + 2 * t) = make_float2(vi.x / nrm, vi.y / nrm);
}

// ---------------- 2. sims = dbn[0:4096] * dbn^T  (fp32, 128x128x32 tiles) ----
#define BM 128
#define BN 128
#define BKK 32
#define LDP (BM + 4)

__global__ __launch_bounds__(256) void gemm_nt() {
    __shared__ float As[BKK][LDP];
    __shared__ float Bs[BKK][LDP];
    int bm = blockIdx.y, bn = blockIdx.x;
    int t = threadIdx.x;
    int tx = t & 15, ty = t >> 4;
    const float* Ab = g_dbn + (size_t)bm * BM * DD;
    const float* Bb = g_dbn + (size_t)bn * BN * DD;
    float acc[8][8] = {{0.0f}};
    for (int k0 = 0; k0 < DD; k0 += BKK) {
#pragma unroll
        for (int i = 0; i < 4; ++i) {
            int id = t + i * 256;        // 0..1023 float4-slots per operand
            int row = id >> 3;           // 0..127
            int c4 = (id & 7) << 2;      // 0,4,..,28
            float4 va = *(const float4*)(Ab + (size_t)row * DD + k0 + c4);
            float4 vb = *(const float4*)(Bb + (size_t)row * DD + k0 + c4);
            As[c4 + 0][row] = va.x; As[c4 + 1][row] = va.y; As[c4 + 2][row] = va.z; As[c4 + 3][row] = va.w;
            Bs[c4 + 0][row] = vb.x; Bs[c4 + 1][row] = vb.y; Bs[c4 + 2][row] = vb.z; Bs[c4 + 3][row] = vb.w;
        }
        __syncthreads();
#pragma unroll
        for (int kk = 0; kk < BKK; ++kk) {
            float a[8], b[8];
            *(float4*)(a)     = *(const float4*)&As[kk][ty * 8];
            *(float4*)(a + 4) = *(const float4*)&As[kk][ty * 8 + 4];
            *(float4*)(b)     = *(const float4*)&Bs[kk][tx * 8];
            *(float4*)(b + 4) = *(const float4*)&Bs[kk][tx * 8 + 4];
#pragma unroll
            for (int i = 0; i < 8; ++i)
#pragma unroll
                for (int j = 0; j < 8; ++j)
                    acc[i][j] = fmaf(a[i], b[j], acc[i][j]);
        }
        __syncthreads();
    }
    int r0 = bm * BM + ty * 8;
    int c0 = bn * BN + tx * 8;
#pragma unroll
    for (int i = 0; i < 8; ++i) {
        float* cp = g_sims + (size_t)(r0 + i) * NDB + c0;
        *(float4*)cp       = *(float4*)&acc[i][0];
        *(float4*)(cp + 4) = *(float4*)&acc[i][4];
    }
}

// ---------------- 3. exact top-32 per row, numpy tie semantics ---------------
__global__ __launch_bounds__(256) void topk_kernel() {
    __shared__ unsigned keys[NDB];                 // 48 KB
    __shared__ unsigned long long cmax[NDB / 64];  // 192 chunk maxima
    __shared__ unsigned long long wpart[4];
    __shared__ int s_widx;
    int b = blockIdx.x, t = threadIdx.x;
    const float* row = g_sims + (size_t)b * NDB;
    for (int i = t; i < NDB / 4; i += 256) {
        float4 v = *(const float4*)(row + 4 * i);
        keys[4 * i + 0] = fkey(v.x);
        keys[4 * i + 1] = fkey(v.y);
        keys[4 * i + 2] = fkey(v.z);
        keys[4 * i + 3] = fkey(v.w);
    }
    __syncthreads();
    int wave = t >> 6, lane = t & 63;
    for (int c = wave; c < NDB / 64; c += 4) {
        int idx = c * 64 + lane;
        unsigned long long kk = ((unsigned long long)keys[idx] << 32) | (unsigned)(~idx);
#pragma unroll
        for (int o = 32; o > 0; o >>= 1) {
            unsigned long long other = __shfl_down(kk, o);
            kk = other > kk ? other : kk;
        }
        if (lane == 0) cmax[c] = kk;
    }
    __syncthreads();
    for (int it = 0; it < KTOP; ++it) {
        unsigned long long kk = (t < NDB / 64) ? cmax[t] : 0ull;
#pragma unroll
        for (int o = 32; o > 0; o >>= 1) {
            unsigned long long other = __shfl_down(kk, o);
            kk = other > kk ? other : kk;
        }
        if (lane == 0) wpart[wave] = kk;
        __syncthreads();
        if (t == 0) {
            unsigned long long w = wpart[0];
#pragma unroll
            for (int i = 1; i < 4; ++i) w = wpart[i] > w ? wpart[i] : w;
            int idx = (int)(~(unsigned)w);
            g_topk[b * KTOP + it] = idx;
            keys[idx] = 0;          // remove extracted element
            s_widx = idx;
        }
        __syncthreads();
        if (wave == 0) {            // re-reduce only the winner's chunk
            int c = s_widx >> 6;
            int idx = c * 64 + lane;
            unsigned long long kk2 = ((unsigned long long)keys[idx] << 32) | (unsigned)(~idx);
#pragma unroll
            for (int o = 32; o > 0; o >>= 1) {
                unsigned long long other = __shfl_down(kk2, o);
                kk2 = other > kk2 ? other : kk2;
            }
            if (lane == 0) cmax[c] = kk2;
        }
        __syncthreads();
    }
}

// ---------------- 4. circular-mean aggregation + blend -----------------------
__global__ __launch_bounds__(256) void agg_kernel(
        const float* __restrict__ x_real, const float* __restrict__ x_imag,
        const float* __restrict__ att_real, const float* __restrict__ att_imag,
        const float* __restrict__ alpha_p, float* __restrict__ out) {
    __shared__ int idxs[KTOP];
    int b = blockIdx.x, t = threadIdx.x;
    if (t < KTOP) idxs[t] = g_topk[b * KTOP + t];
    __syncthreads();
    float a = alpha_p[0];
    a = fminf(fmaxf(a, 0.0f), 1.0f);
    int f = 2 * t;
    float sr0 = 0, sc0 = 0, ss0 = 0, sr1 = 0, sc1 = 0, ss1 = 0;
    for (int k = 0; k < KTOP; ++k) {
        int idx = idxs[k];
        const float *re, *im;
        if (idx < BQ) { re = x_real + (size_t)idx * FD;          im = x_imag + (size_t)idx * FD; }
        else          { re = att_real + (size_t)(idx - BQ) * FD; im = att_imag + (size_t)(idx - BQ) * FD; }
        float2 vr = *(const float2*)(re + f);
        float2 vi = *(const float2*)(im + f);
        float r0 = sqrtf(vr.x * vr.x + vi.x * vi.x);
        sr0 += r0;
        if (r0 > 0.0f) { sc0 += vr.x / r0; ss0 += vi.x / r0; } else { sc0 += 1.0f; }  // atan2(0,0)=0
        float r1 = sqrtf(vr.y * vr.y + vi.y * vi.y);
        sr1 += r1;
        if (r1 > 0.0f) { sc1 += vr.y / r1; ss1 += vi.y / r1; } else { sc1 += 1.0f; }
    }
    const float inv = 1.0f / KTOP;
    float mr0 = sr0 * inv + EPSF, mc0 = sc0 * inv, ms0 = ss0 * inv;
    float mr1 = sr1 * inv + EPSF, mc1 = sc1 * inv, ms1 = ss1 * inv;
    float R0 = sqrtf(mc0 * mc0 + ms0 * ms0);
    float R1 = sqrtf(mc1 * mc1 + ms1 * ms1);
    float c0 = (R0 > 0.0f) ? mc0 / R0 : 1.0f;
    float s0 = (R0 > 0.0f) ? ms0 / R0 : 0.0f;
    float c1 = (R1 > 0.0f) ? mc1 / R1 : 1.0f;
    float s1 = (R1 > 0.0f) ? ms1 / R1 : 0.0f;
    size_t obase = (size_t)b * FD + f;
    float2 xr = *(const float2*)(x_real + obase);
    float2 xi = *(const float2*)(x_imag + obase);
    float2 outr = make_float2((1.0f - a) * xr.x + a * (mr0 * c0),
                              (1.0f - a) * xr.y + a * (mr1 * c1));
    float2 outi = make_float2((1.0f - a) * xi.x + a * (mr0 * s0),
                              (1.0f - a) * xi.y + a * (mr1 * s1));
    *(float2*)(out + obase) = outr;
    *(float2*)(out + (size_t)BQ * FD + obase) = outi;
}

extern "C" void kernel_launch(void* const* d_in, const int* in_sizes, int n_in,
                              void* d_out, int out_size, void* d_ws, size_t ws_size,
                              hipStream_t stream) {
    const float* x_real   = (const float*)d_in[0];
    const float* x_imag   = (const float*)d_in[1];
    const float* att_real = (const float*)d_in[2];
    const float* att_imag = (const float*)d_in[3];
    const float* alpha    = (const float*)d_in[4];
    float* out = (float*)d_out;

    normalize_kernel<<<NDB, 256, 0, stream>>>(x_real, x_imag, att_real, att_imag);
    gemm_nt<<<dim3(NDB / BN, BQ / BM), 256, 0, stream>>>();
    topk_kernel<<<BQ, 256, 0, stream>>>();
    agg_kernel<<<BQ, 256, 0, stream>>>(x_real, x_imag, att_real, att_imag, alpha, out);
}

// Round 2
// 907.355 us; speedup vs baseline: 1.7675x; 1.7675x over previous
//
#include <hip/hip_runtime.h>
#include <math.h>

#define BQ   4096
#define FD   512
#define NATT 8192
#define NDB  (BQ + NATT)   // 12288
#define DD   (2 * FD)      // 1024
#define KTOP 32
#define EPSF 1e-7f

typedef __attribute__((ext_vector_type(8))) short bf16x8;
typedef __attribute__((ext_vector_type(4))) float f32x4;

// Static device scratch — fully rewritten before every read within one call.
__device__ unsigned short g_hi[(size_t)NDB * DD];  // 24 MB bf16 hi of normalized db
__device__ unsigned short g_lo[(size_t)NDB * DD];  // 24 MB bf16 lo residual
__device__ float g_sims[(size_t)BQ * NDB];         // 201 MB similarity matrix
__device__ int   g_topk[BQ * KTOP];

__device__ __forceinline__ unsigned fkey(float f) {
    unsigned u = __float_as_uint(f);
    return (u & 0x80000000u) ? ~u : (u | 0x80000000u);  // monotonic float->uint
}
__device__ __forceinline__ unsigned short f2bf(float f) {   // RNE f32->bf16
    unsigned u = __float_as_uint(f);
    return (unsigned short)((u + 0x7FFFu + ((u >> 16) & 1u)) >> 16);
}
__device__ __forceinline__ float bf2f(unsigned short h) {
    return __uint_as_float((unsigned)h << 16);
}
__device__ __forceinline__ void gld16(const void* g, void* l) {
    __builtin_amdgcn_global_load_lds(
        (const __attribute__((address_space(1))) void*)g,
        (__attribute__((address_space(3))) void*)l, 16, 0, 0);
}

// ---------------- 1. L2-normalize db rows, emit bf16 hi/lo -------------------
__global__ __launch_bounds__(256) void normalize_kernel(
        const float* __restrict__ x_real, const float* __restrict__ x_imag,
        const float* __restrict__ att_real, const float* __restrict__ att_imag) {
    int row = blockIdx.x;
    int t = threadIdx.x;
    const float *re, *im;
    if (row < BQ) { re = x_real + (size_t)row * FD;        im = x_imag + (size_t)row * FD; }
    else          { re = att_real + (size_t)(row - BQ) * FD; im = att_imag + (size_t)(row - BQ) * FD; }
    float2 vr = *(const float2*)(re + 2 * t);
    float2 vi = *(const float2*)(im + 2 * t);
    float ss = vr.x * vr.x + vr.y * vr.y + vi.x * vi.x + vi.y * vi.y;
#pragma unroll
    for (int o = 32; o > 0; o >>= 1) ss += __shfl_down(ss, o);
    __shared__ float wsum[4];
    __shared__ float s_norm;
    if ((t & 63) == 0) wsum[t >> 6] = ss;
    __syncthreads();
    if (t == 0) s_norm = sqrtf(wsum[0] + wsum[1] + wsum[2] + wsum[3]);
    __syncthreads();
    float nrm = s_norm;
    size_t base = (size_t)row * DD;
    float n0 = vr.x / nrm, n1 = vr.y / nrm;
    float m0 = vi.x / nrm, m1 = vi.y / nrm;
    ushort2 hr, lr, hi2, li2;
    hr.x = f2bf(n0); lr.x = f2bf(n0 - bf2f(hr.x));
    hr.y = f2bf(n1); lr.y = f2bf(n1 - bf2f(hr.y));
    hi2.x = f2bf(m0); li2.x = f2bf(m0 - bf2f(hi2.x));
    hi2.y = f2bf(m1); li2.y = f2bf(m1 - bf2f(hi2.y));
    *(ushort2*)(g_hi + base + 2 * t)      = hr;
    *(ushort2*)(g_lo + base + 2 * t)      = lr;
    *(ushort2*)(g_hi + base + FD + 2 * t) = hi2;
    *(ushort2*)(g_lo + base + FD + 2 * t) = li2;
}

// ---------------- 2. sims via bf16x3 MFMA (hi*hi + hi*lo + lo*hi) ------------
// 128x128 tile, BK=32, 4 waves x (4x4) 16x16x32 fragments.
// LDS per operand: [4 kc][128 row][8 k] bf16 = 8KB; 4 operands = 32KB.
__global__ __launch_bounds__(256) void gemm_mfma() {
    __shared__ unsigned short smem[4 * 4096];
    const int t = threadIdx.x;
    const int lane = t & 63, wid = t >> 6;
    const int wr = wid >> 1, wc = wid & 1;
    const int kc = lane >> 4, fr = lane & 15;
    const int bm = blockIdx.y, bn = blockIdx.x;
    const unsigned short* aph = g_hi + (size_t)bm * 128 * DD;
    const unsigned short* apl = g_lo + (size_t)bm * 128 * DD;
    const unsigned short* bph = g_hi + (size_t)bn * 128 * DD;
    const unsigned short* bpl = g_lo + (size_t)bn * 128 * DD;

    f32x4 acc[4][4];
#pragma unroll
    for (int m = 0; m < 4; ++m)
#pragma unroll
        for (int n = 0; n < 4; ++n) acc[m][n] = (f32x4){0.f, 0.f, 0.f, 0.f};

    // staging slots: n in [0,512) -> kc = n>>7, row = n&127; thread t owns t, t+256
    const int s0 = t, s1 = t + 256;
    const int r0 = s0 & 127, c0 = (s0 >> 7) * 8;
    const int r1 = s1 & 127, c1 = (s1 >> 7) * 8;

    for (int k0 = 0; k0 < DD; k0 += 32) {
        gld16(aph + (size_t)r0 * DD + k0 + c0, &smem[0 * 4096 + s0 * 8]);
        gld16(aph + (size_t)r1 * DD + k0 + c1, &smem[0 * 4096 + s1 * 8]);
        gld16(apl + (size_t)r0 * DD + k0 + c0, &smem[1 * 4096 + s0 * 8]);
        gld16(apl + (size_t)r1 * DD + k0 + c1, &smem[1 * 4096 + s1 * 8]);
        gld16(bph + (size_t)r0 * DD + k0 + c0, &smem[2 * 4096 + s0 * 8]);
        gld16(bph + (size_t)r1 * DD + k0 + c1, &smem[2 * 4096 + s1 * 8]);
        gld16(bpl + (size_t)r0 * DD + k0 + c0, &smem[3 * 4096 + s0 * 8]);
        gld16(bpl + (size_t)r1 * DD + k0 + c1, &smem[3 * 4096 + s1 * 8]);
        __syncthreads();  // drains vmcnt -> staged tile visible

        bf16x8 ah[4], al[4], bh[4], bl[4];
#pragma unroll
        for (int m = 0; m < 4; ++m) {
            int ra = wr * 64 + m * 16 + fr;
            ah[m] = *(const bf16x8*)&smem[0 * 4096 + (kc * 128 + ra) * 8];
            al[m] = *(const bf16x8*)&smem[1 * 4096 + (kc * 128 + ra) * 8];
            int rb = wc * 64 + m * 16 + fr;
            bh[m] = *(const bf16x8*)&smem[2 * 4096 + (kc * 128 + rb) * 8];
            bl[m] = *(const bf16x8*)&smem[3 * 4096 + (kc * 128 + rb) * 8];
        }
#pragma unroll
        for (int m = 0; m < 4; ++m)
#pragma unroll
            for (int n = 0; n < 4; ++n) {
                acc[m][n] = __builtin_amdgcn_mfma_f32_16x16x32_bf16(ah[m], bh[n], acc[m][n], 0, 0, 0);
                acc[m][n] = __builtin_amdgcn_mfma_f32_16x16x32_bf16(ah[m], bl[n], acc[m][n], 0, 0, 0);
                acc[m][n] = __builtin_amdgcn_mfma_f32_16x16x32_bf16(al[m], bh[n], acc[m][n], 0, 0, 0);
            }
        __syncthreads();
    }
    // epilogue: C/D layout col=lane&15, row=(lane>>4)*4+j
    const int crow0 = bm * 128 + wr * 64 + kc * 4;
    const int ccol0 = bn * 128 + wc * 64 + fr;
#pragma unroll
    for (int m = 0; m < 4; ++m)
#pragma unroll
        for (int n = 0; n < 4; ++n)
#pragma unroll
            for (int j = 0; j < 4; ++j)
                g_sims[(size_t)(crow0 + m * 16 + j) * NDB + ccol0 + n * 16] = acc[m][n][j];
}

// ---------------- 3. exact top-32 per row, numpy tie semantics ---------------
__global__ __launch_bounds__(256) void topk_kernel() {
    __shared__ unsigned keys[NDB];                 // 48 KB
    __shared__ unsigned long long cmax[NDB / 64];  // 192 chunk maxima
    __shared__ unsigned long long wpart[4];
    __shared__ int s_widx;
    int b = blockIdx.x, t = threadIdx.x;
    const float* row = g_sims + (size_t)b * NDB;
    for (int i = t; i < NDB / 4; i += 256) {
        float4 v = *(const float4*)(row + 4 * i);
        keys[4 * i + 0] = fkey(v.x);
        keys[4 * i + 1] = fkey(v.y);
        keys[4 * i + 2] = fkey(v.z);
        keys[4 * i + 3] = fkey(v.w);
    }
    __syncthreads();
    int wave = t >> 6, lane = t & 63;
    for (int c = wave; c < NDB / 64; c += 4) {
        int idx = c * 64 + lane;
        unsigned long long kk = ((unsigned long long)keys[idx] << 32) | (unsigned)(~idx);
#pragma unroll
        for (int o = 32; o > 0; o >>= 1) {
            unsigned long long other = __shfl_down(kk, o);
            kk = other > kk ? other : kk;
        }
        if (lane == 0) cmax[c] = kk;
    }
    __syncthreads();
    for (int it = 0; it < KTOP; ++it) {
        unsigned long long kk = (t < NDB / 64) ? cmax[t] : 0ull;
#pragma unroll
        for (int o = 32; o > 0; o >>= 1) {
            unsigned long long other = __shfl_down(kk, o);
            kk = other > kk ? other : kk;
        }
        if (lane == 0) wpart[wave] = kk;
        __syncthreads();
        if (t == 0) {
            unsigned long long w = wpart[0];
#pragma unroll
            for (int i = 1; i < 4; ++i) w = wpart[i] > w ? wpart[i] : w;
            int idx = (int)(~(unsigned)w);
            g_topk[b * KTOP + it] = idx;
            keys[idx] = 0;          // remove extracted element
            s_widx = idx;
        }
        __syncthreads();
        if (wave == 0) {            // re-reduce only the winner's chunk
            int c = s_widx >> 6;
            int idx = c * 64 + lane;
            unsigned long long kk2 = ((unsigned long long)keys[idx] << 32) | (unsigned)(~idx);
#pragma unroll
            for (int o = 32; o > 0; o >>= 1) {
                unsigned long long other = __shfl_down(kk2, o);
                kk2 = other > kk2 ? other : kk2;
            }
            if (lane == 0) cmax[c] = kk2;
        }
        __syncthreads();
    }
}

// ---------------- 4. circular-mean aggregation + blend -----------------------
__global__ __launch_bounds__(256) void agg_kernel(
        const float* __restrict__ x_real, const float* __restrict__ x_imag,
        const float* __restrict__ att_real, const float* __restrict__ att_imag,
        const float* __restrict__ alpha_p, float* __restrict__ out) {
    __shared__ int idxs[KTOP];
    int b = blockIdx.x, t = threadIdx.x;
    if (t < KTOP) idxs[t] = g_topk[b * KTOP + t];
    __syncthreads();
    float a = alpha_p[0];
    a = fminf(fmaxf(a, 0.0f), 1.0f);
    int f = 2 * t;
    float sr0 = 0, sc0 = 0, ss0 = 0, sr1 = 0, sc1 = 0, ss1 = 0;
    for (int k = 0; k < KTOP; ++k) {
        int idx = idxs[k];
        const float *re, *im;
        if (idx < BQ) { re = x_real + (size_t)idx * FD;          im = x_imag + (size_t)idx * FD; }
        else          { re = att_real + (size_t)(idx - BQ) * FD; im = att_imag + (size_t)(idx - BQ) * FD; }
        float2 vr = *(const float2*)(re + f);
        float2 vi = *(const float2*)(im + f);
        float r0 = sqrtf(vr.x * vr.x + vi.x * vi.x);
        sr0 += r0;
        if (r0 > 0.0f) { sc0 += vr.x / r0; ss0 += vi.x / r0; } else { sc0 += 1.0f; }  // atan2(0,0)=0
        float r1 = sqrtf(vr.y * vr.y + vi.y * vi.y);
        sr1 += r1;
        if (r1 > 0.0f) { sc1 += vr.y / r1; ss1 += vi.y / r1; } else { sc1 += 1.0f; }
    }
    const float inv = 1.0f / KTOP;
    float mr0 = sr0 * inv + EPSF, mc0 = sc0 * inv, ms0 = ss0 * inv;
    float mr1 = sr1 * inv + EPSF, mc1 = sc1 * inv, ms1 = ss1 * inv;
    float R0 = sqrtf(mc0 * mc0 + ms0 * ms0);
    float R1 = sqrtf(mc1 * mc1 + ms1 * ms1);
    float c0 = (R0 > 0.0f) ? mc0 / R0 : 1.0f;
    float s0 = (R0 > 0.0f) ? ms0 / R0 : 0.0f;
    float c1 = (R1 > 0.0f) ? mc1 / R1 : 1.0f;
    float s1 = (R1 > 0.0f) ? ms1 / R1 : 0.0f;
    size_t obase = (size_t)b * FD + f;
    float2 xr = *(const float2*)(x_real + obase);
    float2 xi = *(const float2*)(x_imag + obase);
    float2 outr = make_float2((1.0f - a) * xr.x + a * (mr0 * c0),
                              (1.0f - a) * xr.y + a * (mr1 * c1));
    float2 outi = make_float2((1.0f - a) * xi.x + a * (mr0 * s0),
                              (1.0f - a) * xi.y + a * (mr1 * s1));
    *(float2*)(out + obase) = outr;
    *(float2*)(out + (size_t)BQ * FD + obase) = outi;
}

extern "C" void kernel_launch(void* const* d_in, const int* in_sizes, int n_in,
                              void* d_out, int out_size, void* d_ws, size_t ws_size,
                              hipStream_t stream) {
    const float* x_real   = (const float*)d_in[0];
    const float* x_imag   = (const float*)d_in[1];
    const float* att_real = (const float*)d_in[2];
    const float* att_imag = (const float*)d_in[3];
    const float* alpha    = (const float*)d_in[4];
    float* out = (float*)d_out;

    normalize_kernel<<<NDB, 256, 0, stream>>>(x_real, x_imag, att_real, att_imag);
    gemm_mfma<<<dim3(NDB / 128, BQ / 128), 256, 0, stream>>>();
    topk_kernel<<<BQ, 256, 0, stream>>>();
    agg_kernel<<<BQ, 256, 0, stream>>>(x_real, x_imag, att_real, att_imag, alpha, out);
}

// Round 3
// 715.447 us; speedup vs baseline: 2.2416x; 1.2682x over previous
//
#include <hip/hip_runtime.h>
#include <math.h>

#define BQ   4096
#define FD   512
#define NATT 8192
#define NDB  (BQ + NATT)   // 12288
#define DD   (2 * FD)      // 1024
#define KTOP 32
#define EPSF 1e-7f

typedef __attribute__((ext_vector_type(8))) short bf16x8;
typedef __attribute__((ext_vector_type(4))) float f32x4;

// Packed pre-tiled db: [panel(96)][kchunk(32)][hi|lo(2)][kc(4)][row(128)][8]
// panel = row/128, kchunk = k/32, kc = (k>>3)&3.  16B-aligned bursts for staging.
__device__ unsigned short g_pk[(size_t)NDB * DD * 2];  // 48 MB
__device__ float g_sims[(size_t)BQ * NDB];             // 201 MB
__device__ int   g_topk[BQ * KTOP];

__device__ __forceinline__ unsigned fkey(float f) {
    unsigned u = __float_as_uint(f);
    return (u & 0x80000000u) ? ~u : (u | 0x80000000u);  // monotonic float->uint
}
__device__ __forceinline__ unsigned short f2bf(float f) {   // RNE f32->bf16
    unsigned u = __float_as_uint(f);
    return (unsigned short)((u + 0x7FFFu + ((u >> 16) & 1u)) >> 16);
}
__device__ __forceinline__ float bf2f(unsigned short h) {
    return __uint_as_float((unsigned)h << 16);
}
__device__ __forceinline__ void gld16(const void* g, void* l) {
    __builtin_amdgcn_global_load_lds(
        (const __attribute__((address_space(1))) void*)g,
        (__attribute__((address_space(3))) void*)l, 16, 0, 0);
}
// element offset inside g_pk for (row, k, hl)
__device__ __forceinline__ size_t pk_off(int row, int k, int hl) {
    return ((size_t)((row >> 7) * 32 + (k >> 5)) * 2 + hl) * 4096
         + (size_t)(((k >> 3) & 3) * 1024 + (row & 127) * 8 + (k & 7));
}

// ---------------- 1. L2-normalize db rows, emit packed bf16 hi/lo ------------
__global__ __launch_bounds__(256) void normalize_kernel(
        const float* __restrict__ x_real, const float* __restrict__ x_imag,
        const float* __restrict__ att_real, const float* __restrict__ att_imag) {
    int row = blockIdx.x;
    int t = threadIdx.x;
    const float *re, *im;
    if (row < BQ) { re = x_real + (size_t)row * FD;        im = x_imag + (size_t)row * FD; }
    else          { re = att_real + (size_t)(row - BQ) * FD; im = att_imag + (size_t)(row - BQ) * FD; }
    float2 vr = *(const float2*)(re + 2 * t);
    float2 vi = *(const float2*)(im + 2 * t);
    float ss = vr.x * vr.x + vr.y * vr.y + vi.x * vi.x + vi.y * vi.y;
#pragma unroll
    for (int o = 32; o > 0; o >>= 1) ss += __shfl_down(ss, o);
    __shared__ float wsum[4];
    __shared__ float s_norm;
    if ((t & 63) == 0) wsum[t >> 6] = ss;
    __syncthreads();
    if (t == 0) s_norm = sqrtf(wsum[0] + wsum[1] + wsum[2] + wsum[3]);
    __syncthreads();
    float nrm = s_norm;
    int k1 = 2 * t;        // real part -> k1, k1+1
    int k2 = FD + 2 * t;   // imag part -> k2, k2+1
    float n0 = vr.x / nrm, n1 = vr.y / nrm;
    float m0 = vi.x / nrm, m1 = vi.y / nrm;
    ushort2 hr, lr, hi2, li2;
    hr.x = f2bf(n0); lr.x = f2bf(n0 - bf2f(hr.x));
    hr.y = f2bf(n1); lr.y = f2bf(n1 - bf2f(hr.y));
    hi2.x = f2bf(m0); li2.x = f2bf(m0 - bf2f(hi2.x));
    hi2.y = f2bf(m1); li2.y = f2bf(m1 - bf2f(hi2.y));
    *(ushort2*)(g_pk + pk_off(row, k1, 0)) = hr;
    *(ushort2*)(g_pk + pk_off(row, k1, 1)) = lr;
    *(ushort2*)(g_pk + pk_off(row, k2, 0)) = hi2;
    *(ushort2*)(g_pk + pk_off(row, k2, 1)) = li2;
}

// ---------------- 2. sims via bf16x3 MFMA (hi*hi + hi*lo + lo*hi) ------------
// 128x128 tile, BK=32, 4 waves x (4x4) 16x16x32 fragments.
// LDS: A[hi 4K][lo 4K] + B[hi 4K][lo 4K] elements = 32KB, each staged as one
// contiguous 16KB global burst (lane-contiguous -> full cache-line use).
__global__ __launch_bounds__(256) void gemm_mfma() {
    __shared__ unsigned short smem[4 * 4096];
    const int t = threadIdx.x;
    const int lane = t & 63, wid = t >> 6;
    const int wr = wid >> 1, wc = wid & 1;
    const int kc = lane >> 4, fr = lane & 15;
    const int bm = blockIdx.y, bn = blockIdx.x;

    f32x4 acc[4][4];
#pragma unroll
    for (int m = 0; m < 4; ++m)
#pragma unroll
        for (int n = 0; n < 4; ++n) acc[m][n] = (f32x4){0.f, 0.f, 0.f, 0.f};

    for (int c = 0; c < 32; ++c) {   // k0 = 32*c
        const unsigned short* apk = g_pk + ((size_t)(bm * 32 + c)) * 8192;
        const unsigned short* bpk = g_pk + ((size_t)(bn * 32 + c)) * 8192;
#pragma unroll
        for (int i = 0; i < 4; ++i) {
            int s = t + i * 256;                       // 0..1023 16B slots
            gld16(apk + (size_t)s * 8, &smem[s * 8]);
            gld16(bpk + (size_t)s * 8, &smem[8192 + s * 8]);
        }
        __syncthreads();  // drains vmcnt -> staged tile visible

        bf16x8 ah[4], al[4], bh[4], bl[4];
#pragma unroll
        for (int m = 0; m < 4; ++m) {
            int ra = wr * 64 + m * 16 + fr;
            ah[m] = *(const bf16x8*)&smem[(kc * 128 + ra) * 8];
            al[m] = *(const bf16x8*)&smem[4096 + (kc * 128 + ra) * 8];
            int rb = wc * 64 + m * 16 + fr;
            bh[m] = *(const bf16x8*)&smem[8192 + (kc * 128 + rb) * 8];
            bl[m] = *(const bf16x8*)&smem[12288 + (kc * 128 + rb) * 8];
        }
#pragma unroll
        for (int m = 0; m < 4; ++m)
#pragma unroll
            for (int n = 0; n < 4; ++n) {
                acc[m][n] = __builtin_amdgcn_mfma_f32_16x16x32_bf16(ah[m], bh[n], acc[m][n], 0, 0, 0);
                acc[m][n] = __builtin_amdgcn_mfma_f32_16x16x32_bf16(ah[m], bl[n], acc[m][n], 0, 0, 0);
                acc[m][n] = __builtin_amdgcn_mfma_f32_16x16x32_bf16(al[m], bh[n], acc[m][n], 0, 0, 0);
            }
        __syncthreads();
    }
    // epilogue: C/D layout col=lane&15, row=(lane>>4)*4+j
    const int crow0 = bm * 128 + wr * 64 + kc * 4;
    const int ccol0 = bn * 128 + wc * 64 + fr;
#pragma unroll
    for (int m = 0; m < 4; ++m)
#pragma unroll
        for (int n = 0; n < 4; ++n)
#pragma unroll
            for (int j = 0; j < 4; ++j)
                g_sims[(size_t)(crow0 + m * 16 + j) * NDB + ccol0 + n * 16] = acc[m][n][j];
}

// ---------------- 3. exact top-32 per row, numpy tie semantics ---------------
__global__ __launch_bounds__(256) void topk_kernel() {
    __shared__ unsigned keys[NDB];                 // 48 KB
    __shared__ unsigned long long cmax[NDB / 64];  // 192 chunk maxima
    __shared__ unsigned long long wpart[4];
    __shared__ int s_widx;
    int b = blockIdx.x, t = threadIdx.x;
    const float* row = g_sims + (size_t)b * NDB;
    for (int i = t; i < NDB / 4; i += 256) {
        float4 v = *(const float4*)(row + 4 * i);
        keys[4 * i + 0] = fkey(v.x);
        keys[4 * i + 1] = fkey(v.y);
        keys[4 * i + 2] = fkey(v.z);
        keys[4 * i + 3] = fkey(v.w);
    }
    __syncthreads();
    int wave = t >> 6, lane = t & 63;
    for (int c = wave; c < NDB / 64; c += 4) {
        int idx = c * 64 + lane;
        unsigned long long kk = ((unsigned long long)keys[idx] << 32) | (unsigned)(~idx);
#pragma unroll
        for (int o = 32; o > 0; o >>= 1) {
            unsigned long long other = __shfl_down(kk, o);
            kk = other > kk ? other : kk;
        }
        if (lane == 0) cmax[c] = kk;
    }
    __syncthreads();
    for (int it = 0; it < KTOP; ++it) {
        unsigned long long kk = (t < NDB / 64) ? cmax[t] : 0ull;
#pragma unroll
        for (int o = 32; o > 0; o >>= 1) {
            unsigned long long other = __shfl_down(kk, o);
            kk = other > kk ? other : kk;
        }
        if (lane == 0) wpart[wave] = kk;
        __syncthreads();
        if (t == 0) {
            unsigned long long w = wpart[0];
#pragma unroll
            for (int i = 1; i < 4; ++i) w = wpart[i] > w ? wpart[i] : w;
            int idx = (int)(~(unsigned)w);
            g_topk[b * KTOP + it] = idx;
            keys[idx] = 0;          // remove extracted element
            s_widx = idx;
        }
        __syncthreads();
        if (wave == 0) {            // re-reduce only the winner's chunk
            int c = s_widx >> 6;
            int idx = c * 64 + lane;
            unsigned long long kk2 = ((unsigned long long)keys[idx] << 32) | (unsigned)(~idx);
#pragma unroll
            for (int o = 32; o > 0; o >>= 1) {
                unsigned long long other = __shfl_down(kk2, o);
                kk2 = other > kk2 ? other : kk2;
            }
            if (lane == 0) cmax[c] = kk2;
        }
        __syncthreads();
    }
}

// ---------------- 4. circular-mean aggregation + blend -----------------------
__global__ __launch_bounds__(256) void agg_kernel(
        const float* __restrict__ x_real, const float* __restrict__ x_imag,
        const float* __restrict__ att_real, const float* __restrict__ att_imag,
        const float* __restrict__ alpha_p, float* __restrict__ out) {
    __shared__ int idxs[KTOP];
    int b = blockIdx.x, t = threadIdx.x;
    if (t < KTOP) idxs[t] = g_topk[b * KTOP + t];
    __syncthreads();
    float a = alpha_p[0];
    a = fminf(fmaxf(a, 0.0f), 1.0f);
    int f = 2 * t;
    float sr0 = 0, sc0 = 0, ss0 = 0, sr1 = 0, sc1 = 0, ss1 = 0;
    for (int k = 0; k < KTOP; ++k) {
        int idx = idxs[k];
        const float *re, *im;
        if (idx < BQ) { re = x_real + (size_t)idx * FD;          im = x_imag + (size_t)idx * FD; }
        else          { re = att_real + (size_t)(idx - BQ) * FD; im = att_imag + (size_t)(idx - BQ) * FD; }
        float2 vr = *(const float2*)(re + f);
        float2 vi = *(const float2*)(im + f);
        float r0 = sqrtf(vr.x * vr.x + vi.x * vi.x);
        sr0 += r0;
        if (r0 > 0.0f) { sc0 += vr.x / r0; ss0 += vi.x / r0; } else { sc0 += 1.0f; }  // atan2(0,0)=0
        float r1 = sqrtf(vr.y * vr.y + vi.y * vi.y);
        sr1 += r1;
        if (r1 > 0.0f) { sc1 += vr.y / r1; ss1 += vi.y / r1; } else { sc1 += 1.0f; }
    }
    const float inv = 1.0f / KTOP;
    float mr0 = sr0 * inv + EPSF, mc0 = sc0 * inv, ms0 = ss0 * inv;
    float mr1 = sr1 * inv + EPSF, mc1 = sc1 * inv, ms1 = ss1 * inv;
    float R0 = sqrtf(mc0 * mc0 + ms0 * ms0);
    float R1 = sqrtf(mc1 * mc1 + ms1 * ms1);
    float c0 = (R0 > 0.0f) ? mc0 / R0 : 1.0f;
    float s0 = (R0 > 0.0f) ? ms0 / R0 : 0.0f;
    float c1 = (R1 > 0.0f) ? mc1 / R1 : 1.0f;
    float s1 = (R1 > 0.0f) ? ms1 / R1 : 0.0f;
    size_t obase = (size_t)b * FD + f;
    float2 xr = *(const float2*)(x_real + obase);
    float2 xi = *(const float2*)(x_imag + obase);
    float2 outr = make_float2((1.0f - a) * xr.x + a * (mr0 * c0),
                              (1.0f - a) * xr.y + a * (mr1 * c1));
    float2 outi = make_float2((1.0f - a) * xi.x + a * (mr0 * s0),
                              (1.0f - a) * xi.y + a * (mr1 * s1));
    *(float2*)(out + obase) = outr;
    *(float2*)(out + (size_t)BQ * FD + obase) = outi;
}

extern "C" void kernel_launch(void* const* d_in, const int* in_sizes, int n_in,
                              void* d_out, int out_size, void* d_ws, size_t ws_size,
                              hipStream_t stream) {
    const float* x_real   = (const float*)d_in[0];
    const float* x_imag   = (const float*)d_in[1];
    const float* att_real = (const float*)d_in[2];
    const float* att_imag = (const float*)d_in[3];
    const float* alpha    = (const float*)d_in[4];
    float* out = (float*)d_out;

    normalize_kernel<<<NDB, 256, 0, stream>>>(x_real, x_imag, att_real, att_imag);
    gemm_mfma<<<dim3(NDB / 128, BQ / 128), 256, 0, stream>>>();
    topk_kernel<<<BQ, 256, 0, stream>>>();
    agg_kernel<<<BQ, 256, 0, stream>>>(x_real, x_imag, att_real, att_imag, alpha, out);
}

// Round 4
// 615.482 us; speedup vs baseline: 2.6057x; 1.1624x over previous
//
#include <hip/hip_runtime.h>
#include <math.h>

#define BQ   4096
#define FD   512
#define NATT 8192
#define NDB  (BQ + NATT)   // 12288
#define DD   (2 * FD)      // 1024
#define KTOP 32
#define EPSF 1e-7f

typedef __attribute__((ext_vector_type(8))) short bf16x8;
typedef __attribute__((ext_vector_type(4))) float f32x4;

// Packed pre-tiled db: [panel(96)][kchunk(32)][hi|lo(2)][kc(4)][row(128)][8]
__device__ unsigned short g_pk[(size_t)NDB * DD * 2];  // 48 MB
__device__ float g_sims[(size_t)BQ * NDB];             // 201 MB
__device__ int   g_topk[BQ * KTOP];

__device__ __forceinline__ unsigned fkey(unsigned u) {
    return u ^ (unsigned)(((int)u >> 31) | 0x80000000);  // monotonic float->uint, 2 VALU
}
__device__ __forceinline__ unsigned short f2bf(float f) {   // RNE f32->bf16
    unsigned u = __float_as_uint(f);
    return (unsigned short)((u + 0x7FFFu + ((u >> 16) & 1u)) >> 16);
}
__device__ __forceinline__ float bf2f(unsigned short h) {
    return __uint_as_float((unsigned)h << 16);
}
__device__ __forceinline__ void gld16(const void* g, void* l) {
    __builtin_amdgcn_global_load_lds(
        (const __attribute__((address_space(1))) void*)g,
        (__attribute__((address_space(3))) void*)l, 16, 0, 0);
}
__device__ __forceinline__ size_t pk_off(int row, int k, int hl) {
    return ((size_t)((row >> 7) * 32 + (k >> 5)) * 2 + hl) * 4096
         + (size_t)(((k >> 3) & 3) * 1024 + (row & 127) * 8 + (k & 7));
}

// ---------------- 1. L2-normalize db rows, emit packed bf16 hi/lo ------------
__global__ __launch_bounds__(256) void normalize_kernel(
        const float* __restrict__ x_real, const float* __restrict__ x_imag,
        const float* __restrict__ att_real, const float* __restrict__ att_imag) {
    int row = blockIdx.x;
    int t = threadIdx.x;
    const float *re, *im;
    if (row < BQ) { re = x_real + (size_t)row * FD;        im = x_imag + (size_t)row * FD; }
    else          { re = att_real + (size_t)(row - BQ) * FD; im = att_imag + (size_t)(row - BQ) * FD; }
    float2 vr = *(const float2*)(re + 2 * t);
    float2 vi = *(const float2*)(im + 2 * t);
    float ss = vr.x * vr.x + vr.y * vr.y + vi.x * vi.x + vi.y * vi.y;
#pragma unroll
    for (int o = 32; o > 0; o >>= 1) ss += __shfl_down(ss, o);
    __shared__ float wsum[4];
    __shared__ float s_norm;
    if ((t & 63) == 0) wsum[t >> 6] = ss;
    __syncthreads();
    if (t == 0) s_norm = sqrtf(wsum[0] + wsum[1] + wsum[2] + wsum[3]);
    __syncthreads();
    float nrm = s_norm;
    int k1 = 2 * t;        // real part -> k1, k1+1
    int k2 = FD + 2 * t;   // imag part -> k2, k2+1
    float n0 = vr.x / nrm, n1 = vr.y / nrm;
    float m0 = vi.x / nrm, m1 = vi.y / nrm;
    ushort2 hr, lr, hi2, li2;
    hr.x = f2bf(n0); lr.x = f2bf(n0 - bf2f(hr.x));
    hr.y = f2bf(n1); lr.y = f2bf(n1 - bf2f(hr.y));
    hi2.x = f2bf(m0); li2.x = f2bf(m0 - bf2f(hi2.x));
    hi2.y = f2bf(m1); li2.y = f2bf(m1 - bf2f(hi2.y));
    *(ushort2*)(g_pk + pk_off(row, k1, 0)) = hr;
    *(ushort2*)(g_pk + pk_off(row, k1, 1)) = lr;
    *(ushort2*)(g_pk + pk_off(row, k2, 0)) = hi2;
    *(ushort2*)(g_pk + pk_off(row, k2, 1)) = li2;
}

// ---------------- 2. sims via bf16x3 MFMA (hi*hi + hi*lo + lo*hi) ------------
__global__ __launch_bounds__(256) void gemm_mfma() {
    __shared__ unsigned short smem[4 * 4096];
    const int t = threadIdx.x;
    const int lane = t & 63, wid = t >> 6;
    const int wr = wid >> 1, wc = wid & 1;
    const int kc = lane >> 4, fr = lane & 15;
    const int bm = blockIdx.y, bn = blockIdx.x;

    f32x4 acc[4][4];
#pragma unroll
    for (int m = 0; m < 4; ++m)
#pragma unroll
        for (int n = 0; n < 4; ++n) acc[m][n] = (f32x4){0.f, 0.f, 0.f, 0.f};

    for (int c = 0; c < 32; ++c) {   // k0 = 32*c
        const unsigned short* apk = g_pk + ((size_t)(bm * 32 + c)) * 8192;
        const unsigned short* bpk = g_pk + ((size_t)(bn * 32 + c)) * 8192;
#pragma unroll
        for (int i = 0; i < 4; ++i) {
            int s = t + i * 256;                       // 0..1023 16B slots
            gld16(apk + (size_t)s * 8, &smem[s * 8]);
            gld16(bpk + (size_t)s * 8, &smem[8192 + s * 8]);
        }
        __syncthreads();

        bf16x8 ah[4], al[4], bh[4], bl[4];
#pragma unroll
        for (int m = 0; m < 4; ++m) {
            int ra = wr * 64 + m * 16 + fr;
            ah[m] = *(const bf16x8*)&smem[(kc * 128 + ra) * 8];
            al[m] = *(const bf16x8*)&smem[4096 + (kc * 128 + ra) * 8];
            int rb = wc * 64 + m * 16 + fr;
            bh[m] = *(const bf16x8*)&smem[8192 + (kc * 128 + rb) * 8];
            bl[m] = *(const bf16x8*)&smem[12288 + (kc * 128 + rb) * 8];
        }
#pragma unroll
        for (int m = 0; m < 4; ++m)
#pragma unroll
            for (int n = 0; n < 4; ++n) {
                acc[m][n] = __builtin_amdgcn_mfma_f32_16x16x32_bf16(ah[m], bh[n], acc[m][n], 0, 0, 0);
                acc[m][n] = __builtin_amdgcn_mfma_f32_16x16x32_bf16(ah[m], bl[n], acc[m][n], 0, 0, 0);
                acc[m][n] = __builtin_amdgcn_mfma_f32_16x16x32_bf16(al[m], bh[n], acc[m][n], 0, 0, 0);
            }
        __syncthreads();
    }
    const int crow0 = bm * 128 + wr * 64 + kc * 4;
    const int ccol0 = bn * 128 + wc * 64 + fr;
#pragma unroll
    for (int m = 0; m < 4; ++m)
#pragma unroll
        for (int n = 0; n < 4; ++n)
#pragma unroll
            for (int j = 0; j < 4; ++j)
                g_sims[(size_t)(crow0 + m * 16 + j) * NDB + ccol0 + n * 16] = acc[m][n][j];
}

// ---------------- 3. exact top-32: radix-threshold + wave bitonic ------------
// Per row: 1 streaming pass (keys->LDS + 2048-bin histogram of key[31:21]),
// suffix-scan for exact threshold bin, candidate collect, 64-lane bitonic sort.
__global__ __launch_bounds__(256) void topk_kernel() {
    __shared__ unsigned keys[NDB];        // 48 KB
    __shared__ unsigned hist[2048];       // 8 KB
    __shared__ unsigned long long cand[512];
    __shared__ unsigned s_cnt;
    __shared__ int s_thr;
    int b = blockIdx.x, t = threadIdx.x;
    int wave = t >> 6, lane = t & 63;

#pragma unroll
    for (int i = 0; i < 8; ++i) hist[t + 256 * i] = 0;
    if (t == 0) s_cnt = 0;
    __syncthreads();

    const float4* row4 = (const float4*)(g_sims + (size_t)b * NDB);
    float4 v[12];
#pragma unroll
    for (int i = 0; i < 12; ++i) v[i] = row4[t + i * 256];
#pragma unroll
    for (int i = 0; i < 12; ++i) {
        int base = 4 * (t + i * 256);
        unsigned k0 = fkey(__float_as_uint(v[i].x));
        unsigned k1 = fkey(__float_as_uint(v[i].y));
        unsigned k2 = fkey(__float_as_uint(v[i].z));
        unsigned k3 = fkey(__float_as_uint(v[i].w));
        keys[base + 0] = k0; keys[base + 1] = k1;
        keys[base + 2] = k2; keys[base + 3] = k3;
        atomicAdd(&hist[k0 >> 21], 1u);
        atomicAdd(&hist[k1 >> 21], 1u);
        atomicAdd(&hist[k2 >> 21], 1u);
        atomicAdd(&hist[k3 >> 21], 1u);
    }
    __syncthreads();

    if (wave == 0) {   // find largest bin b* with (count of bin >= b*) >= KTOP
        int base = lane * 32;
        unsigned s = 0;
#pragma unroll
        for (int i = 0; i < 32; ++i) s += hist[base + i];
        unsigned suf = s;   // inclusive suffix over lane-chunks
#pragma unroll
        for (int o = 1; o < 64; o <<= 1) {
            unsigned x = __shfl_down(suf, o);
            if (lane + o < 64) suf += x;
        }
        unsigned suf_next = __shfl_down(suf, 1);
        if (lane == 63) suf_next = 0;
        if (suf >= KTOP && suf_next < KTOP) {
            unsigned acc = suf_next;
            int bin = base;
            for (int i = 31; i >= 0; --i) {
                acc += hist[base + i];
                if (acc >= KTOP) { bin = base + i; break; }
            }
            s_thr = bin;
        }
    }
    __syncthreads();

    const unsigned thr = (unsigned)s_thr;
    for (int i = t; i < NDB; i += 256) {
        unsigned k = keys[i];
        if ((k >> 21) >= thr) {
            unsigned p = atomicAdd(&s_cnt, 1u);
            if (p < 512) cand[p] = ((unsigned long long)k << 32) | (unsigned)(~i);
        }
    }
    __syncthreads();

    int c = (int)s_cnt; if (c > 512) c = 512;
    if (c <= 64) {
        if (wave == 0) {
            unsigned long long vv = (lane < c) ? cand[lane] : 0ull;
#pragma unroll
            for (int k = 2; k <= 64; k <<= 1)
#pragma unroll
                for (int j = k >> 1; j > 0; j >>= 1) {
                    unsigned long long o = __shfl_xor(vv, j);
                    bool lower = (lane & j) == 0;
                    bool desc  = (lane & k) == 0;
                    bool keepmax = (lower == desc);
                    vv = keepmax ? (vv > o ? vv : o) : (vv < o ? vv : o);
                }
            if (lane < KTOP) g_topk[b * KTOP + lane] = (int)(~(unsigned)vv);
        }
    } else {
        if (wave == 0) {   // rare fallback: serial extraction over <=512 cands
            for (int it = 0; it < KTOP; ++it) {
                unsigned long long m = 0;
                for (int i = lane; i < c; i += 64) m = cand[i] > m ? cand[i] : m;
#pragma unroll
                for (int o = 32; o > 0; o >>= 1) {
                    unsigned long long x = __shfl_xor(m, o);
                    m = x > m ? x : m;
                }
                if (lane == 0) g_topk[b * KTOP + it] = (int)(~(unsigned)m);
                for (int i = lane; i < c; i += 64) if (cand[i] == m) cand[i] = 0;
            }
        }
    }
}

// ---------------- 4. circular-mean aggregation + blend -----------------------
__global__ __launch_bounds__(256) void agg_kernel(
        const float* __restrict__ x_real, const float* __restrict__ x_imag,
        const float* __restrict__ att_real, const float* __restrict__ att_imag,
        const float* __restrict__ alpha_p, float* __restrict__ out) {
    __shared__ int idxs[KTOP];
    int b = blockIdx.x, t = threadIdx.x;
    if (t < KTOP) idxs[t] = g_topk[b * KTOP + t];
    __syncthreads();
    float a = alpha_p[0];
    a = fminf(fmaxf(a, 0.0f), 1.0f);
    int f = 2 * t;
    float sr0 = 0, sc0 = 0, ss0 = 0, sr1 = 0, sc1 = 0, ss1 = 0;
    for (int k = 0; k < KTOP; ++k) {
        int idx = idxs[k];
        const float *re, *im;
        if (idx < BQ) { re = x_real + (size_t)idx * FD;          im = x_imag + (size_t)idx * FD; }
        else          { re = att_real + (size_t)(idx - BQ) * FD; im = att_imag + (size_t)(idx - BQ) * FD; }
        float2 vr = *(const float2*)(re + f);
        float2 vi = *(const float2*)(im + f);
        float r0 = sqrtf(vr.x * vr.x + vi.x * vi.x);
        sr0 += r0;
        if (r0 > 0.0f) { sc0 += vr.x / r0; ss0 += vi.x / r0; } else { sc0 += 1.0f; }  // atan2(0,0)=0
        float r1 = sqrtf(vr.y * vr.y + vi.y * vi.y);
        sr1 += r1;
        if (r1 > 0.0f) { sc1 += vr.y / r1; ss1 += vi.y / r1; } else { sc1 += 1.0f; }
    }
    const float inv = 1.0f / KTOP;
    float mr0 = sr0 * inv + EPSF, mc0 = sc0 * inv, ms0 = ss0 * inv;
    float mr1 = sr1 * inv + EPSF, mc1 = sc1 * inv, ms1 = ss1 * inv;
    float R0 = sqrtf(mc0 * mc0 + ms0 * ms0);
    float R1 = sqrtf(mc1 * mc1 + ms1 * ms1);
    float c0 = (R0 > 0.0f) ? mc0 / R0 : 1.0f;
    float s0 = (R0 > 0.0f) ? ms0 / R0 : 0.0f;
    float c1 = (R1 > 0.0f) ? mc1 / R1 : 1.0f;
    float s1 = (R1 > 0.0f) ? ms1 / R1 : 0.0f;
    size_t obase = (size_t)b * FD + f;
    float2 xr = *(const float2*)(x_real + obase);
    float2 xi = *(const float2*)(x_imag + obase);
    float2 outr = make_float2((1.0f - a) * xr.x + a * (mr0 * c0),
                              (1.0f - a) * xr.y + a * (mr1 * c1));
    float2 outi = make_float2((1.0f - a) * xi.x + a * (mr0 * s0),
                              (1.0f - a) * xi.y + a * (mr1 * s1));
    *(float2*)(out + obase) = outr;
    *(float2*)(out + (size_t)BQ * FD + obase) = outi;
}

extern "C" void kernel_launch(void* const* d_in, const int* in_sizes, int n_in,
                              void* d_out, int out_size, void* d_ws, size_t ws_size,
                              hipStream_t stream) {
    const float* x_real   = (const float*)d_in[0];
    const float* x_imag   = (const float*)d_in[1];
    const float* att_real = (const float*)d_in[2];
    const float* att_imag = (const float*)d_in[3];
    const float* alpha    = (const float*)d_in[4];
    float* out = (float*)d_out;

    normalize_kernel<<<NDB, 256, 0, stream>>>(x_real, x_imag, att_real, att_imag);
    gemm_mfma<<<dim3(NDB / 128, BQ / 128), 256, 0, stream>>>();
    topk_kernel<<<BQ, 256, 0, stream>>>();
    agg_kernel<<<BQ, 256, 0, stream>>>(x_real, x_imag, att_real, att_imag, alpha, out);
}

// Round 5
// 516.729 us; speedup vs baseline: 3.1037x; 1.1911x over previous
//
#include <hip/hip_runtime.h>
#include <math.h>

#define BQ   4096
#define FD   512
#define NATT 8192
#define NDB  (BQ + NATT)   // 12288
#define DD   (2 * FD)      // 1024
#define KTOP 32
#define EPSF 1e-7f

typedef __attribute__((ext_vector_type(8))) short bf16x8;
typedef __attribute__((ext_vector_type(4))) float f32x4;

// Packed pre-tiled db: [panel(96)][kchunk(32)][hi|lo(2)][kc(4)][row(128)][8]
__device__ unsigned short g_pk[(size_t)NDB * DD * 2];  // 48 MB
__device__ float g_sims[(size_t)BQ * NDB];             // 201 MB

__device__ __forceinline__ unsigned fkey(unsigned u) {
    return u ^ (unsigned)(((int)u >> 31) | 0x80000000);  // monotonic float->uint, 2 VALU
}
__device__ __forceinline__ unsigned short f2bf(float f) {   // RNE f32->bf16
    unsigned u = __float_as_uint(f);
    return (unsigned short)((u + 0x7FFFu + ((u >> 16) & 1u)) >> 16);
}
__device__ __forceinline__ float bf2f(unsigned short h) {
    return __uint_as_float((unsigned)h << 16);
}
__device__ __forceinline__ float frsq(float x) {
#if __has_builtin(__builtin_amdgcn_rsqf)
    return __builtin_amdgcn_rsqf(x);
#else
    return rsqrtf(x);
#endif
}
__device__ __forceinline__ float frcp(float x) {
#if __has_builtin(__builtin_amdgcn_rcpf)
    return __builtin_amdgcn_rcpf(x);
#else
    return 1.0f / x;
#endif
}
__device__ __forceinline__ void gld16(const void* g, void* l) {
    __builtin_amdgcn_global_load_lds(
        (const __attribute__((address_space(1))) void*)g,
        (__attribute__((address_space(3))) void*)l, 16, 0, 0);
}
__device__ __forceinline__ size_t pk_off(int row, int k, int hl) {
    return ((size_t)((row >> 7) * 32 + (k >> 5)) * 2 + hl) * 4096
         + (size_t)(((k >> 3) & 3) * 1024 + (row & 127) * 8 + (k & 7));
}

// ---------------- 1. L2-normalize db rows, emit packed bf16 hi/lo ------------
__global__ __launch_bounds__(256) void normalize_kernel(
        const float* __restrict__ x_real, const float* __restrict__ x_imag,
        const float* __restrict__ att_real, const float* __restrict__ att_imag) {
    int row = blockIdx.x;
    int t = threadIdx.x;
    const float *re, *im;
    if (row < BQ) { re = x_real + (size_t)row * FD;        im = x_imag + (size_t)row * FD; }
    else          { re = att_real + (size_t)(row - BQ) * FD; im = att_imag + (size_t)(row - BQ) * FD; }
    float2 vr = *(const float2*)(re + 2 * t);
    float2 vi = *(const float2*)(im + 2 * t);
    float ss = vr.x * vr.x + vr.y * vr.y + vi.x * vi.x + vi.y * vi.y;
#pragma unroll
    for (int o = 32; o > 0; o >>= 1) ss += __shfl_down(ss, o);
    __shared__ float wsum[4];
    __shared__ float s_norm;
    if ((t & 63) == 0) wsum[t >> 6] = ss;
    __syncthreads();
    if (t == 0) s_norm = sqrtf(wsum[0] + wsum[1] + wsum[2] + wsum[3]);
    __syncthreads();
    float ninv = frcp(s_norm);
    int k1 = 2 * t;        // real part -> k1, k1+1
    int k2 = FD + 2 * t;   // imag part -> k2, k2+1
    float n0 = vr.x * ninv, n1 = vr.y * ninv;
    float m0 = vi.x * ninv, m1 = vi.y * ninv;
    ushort2 hr, lr, hi2, li2;
    hr.x = f2bf(n0); lr.x = f2bf(n0 - bf2f(hr.x));
    hr.y = f2bf(n1); lr.y = f2bf(n1 - bf2f(hr.y));
    hi2.x = f2bf(m0); li2.x = f2bf(m0 - bf2f(hi2.x));
    hi2.y = f2bf(m1); li2.y = f2bf(m1 - bf2f(hi2.y));
    *(ushort2*)(g_pk + pk_off(row, k1, 0)) = hr;
    *(ushort2*)(g_pk + pk_off(row, k1, 1)) = lr;
    *(ushort2*)(g_pk + pk_off(row, k2, 0)) = hi2;
    *(ushort2*)(g_pk + pk_off(row, k2, 1)) = li2;
}

// ---------------- 2. sims via bf16x3 MFMA (hi*hi + hi*lo + lo*hi) ------------
__global__ __launch_bounds__(256) void gemm_mfma() {
    __shared__ unsigned short smem[4 * 4096];
    const int t = threadIdx.x;
    const int lane = t & 63, wid = t >> 6;
    const int wr = wid >> 1, wc = wid & 1;
    const int kc = lane >> 4, fr = lane & 15;
    const int bm = blockIdx.y, bn = blockIdx.x;

    f32x4 acc[4][4];
#pragma unroll
    for (int m = 0; m < 4; ++m)
#pragma unroll
        for (int n = 0; n < 4; ++n) acc[m][n] = (f32x4){0.f, 0.f, 0.f, 0.f};

    for (int c = 0; c < 32; ++c) {   // k0 = 32*c
        const unsigned short* apk = g_pk + ((size_t)(bm * 32 + c)) * 8192;
        const unsigned short* bpk = g_pk + ((size_t)(bn * 32 + c)) * 8192;
#pragma unroll
        for (int i = 0; i < 4; ++i) {
            int s = t + i * 256;                       // 0..1023 16B slots
            gld16(apk + (size_t)s * 8, &smem[s * 8]);
            gld16(bpk + (size_t)s * 8, &smem[8192 + s * 8]);
        }
        __syncthreads();

        bf16x8 ah[4], al[4], bh[4], bl[4];
#pragma unroll
        for (int m = 0; m < 4; ++m) {
            int ra = wr * 64 + m * 16 + fr;
            ah[m] = *(const bf16x8*)&smem[(kc * 128 + ra) * 8];
            al[m] = *(const bf16x8*)&smem[4096 + (kc * 128 + ra) * 8];
            int rb = wc * 64 + m * 16 + fr;
            bh[m] = *(const bf16x8*)&smem[8192 + (kc * 128 + rb) * 8];
            bl[m] = *(const bf16x8*)&smem[12288 + (kc * 128 + rb) * 8];
        }
#pragma unroll
        for (int m = 0; m < 4; ++m)
#pragma unroll
            for (int n = 0; n < 4; ++n) {
                acc[m][n] = __builtin_amdgcn_mfma_f32_16x16x32_bf16(ah[m], bh[n], acc[m][n], 0, 0, 0);
                acc[m][n] = __builtin_amdgcn_mfma_f32_16x16x32_bf16(ah[m], bl[n], acc[m][n], 0, 0, 0);
                acc[m][n] = __builtin_amdgcn_mfma_f32_16x16x32_bf16(al[m], bh[n], acc[m][n], 0, 0, 0);
            }
        __syncthreads();
    }
    const int crow0 = bm * 128 + wr * 64 + kc * 4;
    const int ccol0 = bn * 128 + wc * 64 + fr;
#pragma unroll
    for (int m = 0; m < 4; ++m)
#pragma unroll
        for (int n = 0; n < 4; ++n)
#pragma unroll
            for (int j = 0; j < 4; ++j)
                g_sims[(size_t)(crow0 + m * 16 + j) * NDB + ccol0 + n * 16] = acc[m][n][j];
}

// ------- 3+4 fused: exact top-32 (register radix-threshold) + aggregation ----
// Keys never touch LDS: row lives in 12 float4 registers. One streaming pass
// builds a 2048-bin histogram of key[31:21]; suffix-scan -> exact threshold
// bin; register rescan collects candidates; 64-lane bitonic sorts them; then
// the same block runs the circular-mean aggregation for its query row.
__global__ __launch_bounds__(256) void topk_agg_kernel(
        const float* __restrict__ x_real, const float* __restrict__ x_imag,
        const float* __restrict__ att_real, const float* __restrict__ att_imag,
        const float* __restrict__ alpha_p, float* __restrict__ out) {
    __shared__ unsigned hist[2048];       // 8 KB
    __shared__ unsigned long long cand[512];
    __shared__ int s_idx[KTOP];
    __shared__ unsigned s_cnt;
    __shared__ int s_thr;
    int b = blockIdx.x, t = threadIdx.x;
    int wave = t >> 6, lane = t & 63;

#pragma unroll
    for (int i = 0; i < 8; ++i) hist[t + 256 * i] = 0;
    if (t == 0) s_cnt = 0;
    __syncthreads();

    const float4* row4 = (const float4*)(g_sims + (size_t)b * NDB);
    float4 v[12];
#pragma unroll
    for (int i = 0; i < 12; ++i) v[i] = row4[t + i * 256];
#pragma unroll
    for (int i = 0; i < 12; ++i) {
        atomicAdd(&hist[fkey(__float_as_uint(v[i].x)) >> 21], 1u);
        atomicAdd(&hist[fkey(__float_as_uint(v[i].y)) >> 21], 1u);
        atomicAdd(&hist[fkey(__float_as_uint(v[i].z)) >> 21], 1u);
        atomicAdd(&hist[fkey(__float_as_uint(v[i].w)) >> 21], 1u);
    }
    __syncthreads();

    if (wave == 0) {   // find largest bin b* with (count of bin >= b*) >= KTOP
        int base = lane * 32;
        unsigned s = 0;
#pragma unroll
        for (int i = 0; i < 32; ++i) s += hist[base + i];
        unsigned suf = s;   // inclusive suffix over lane-chunks
#pragma unroll
        for (int o = 1; o < 64; o <<= 1) {
            unsigned x = __shfl_down(suf, o);
            if (lane + o < 64) suf += x;
        }
        unsigned suf_next = __shfl_down(suf, 1);
        if (lane == 63) suf_next = 0;
        if (suf >= KTOP && suf_next < KTOP) {
            unsigned acc = suf_next;
            int bin = base;
            for (int i = 31; i >= 0; --i) {
                acc += hist[base + i];
                if (acc >= KTOP) { bin = base + i; break; }
            }
            s_thr = bin;
        }
    }
    __syncthreads();

    const unsigned thr = (unsigned)s_thr;
#pragma unroll
    for (int i = 0; i < 12; ++i) {
        int base = 4 * (t + i * 256);
        unsigned kk[4] = { fkey(__float_as_uint(v[i].x)), fkey(__float_as_uint(v[i].y)),
                           fkey(__float_as_uint(v[i].z)), fkey(__float_as_uint(v[i].w)) };
#pragma unroll
        for (int j = 0; j < 4; ++j) {
            if ((kk[j] >> 21) >= thr) {
                unsigned p = atomicAdd(&s_cnt, 1u);
                if (p < 512) cand[p] = ((unsigned long long)kk[j] << 32) | (unsigned)(~(base + j));
            }
        }
    }
    __syncthreads();

    int c = (int)s_cnt; if (c > 512) c = 512;
    if (c <= 64) {
        if (wave == 0) {
            unsigned long long vv = (lane < c) ? cand[lane] : 0ull;
#pragma unroll
            for (int k = 2; k <= 64; k <<= 1)
#pragma unroll
                for (int j = k >> 1; j > 0; j >>= 1) {
                    unsigned long long o = __shfl_xor(vv, j);
                    bool lower = (lane & j) == 0;
                    bool desc  = (lane & k) == 0;
                    bool keepmax = (lower == desc);
                    vv = keepmax ? (vv > o ? vv : o) : (vv < o ? vv : o);
                }
            if (lane < KTOP) s_idx[lane] = (int)(~(unsigned)vv);
        }
    } else {
        if (wave == 0) {   // rare fallback: serial extraction over <=512 cands
            for (int it = 0; it < KTOP; ++it) {
                unsigned long long m = 0;
                for (int i = lane; i < c; i += 64) m = cand[i] > m ? cand[i] : m;
#pragma unroll
                for (int o = 32; o > 0; o >>= 1) {
                    unsigned long long x = __shfl_xor(m, o);
                    m = x > m ? x : m;
                }
                if (lane == 0) s_idx[it] = (int)(~(unsigned)m);
                for (int i = lane; i < c; i += 64) if (cand[i] == m) cand[i] = 0;
            }
        }
    }
    __syncthreads();

    // ---- aggregation: circular mean over the 32 neighbors + blend ----
    float a = alpha_p[0];
    a = fminf(fmaxf(a, 0.0f), 1.0f);
    int f = 2 * t;
    float sr0 = 0, sc0 = 0, ss0 = 0, sr1 = 0, sc1 = 0, ss1 = 0;
    for (int k = 0; k < KTOP; ++k) {
        int idx = s_idx[k];
        const float *re, *im;
        if (idx < BQ) { re = x_real + (size_t)idx * FD;          im = x_imag + (size_t)idx * FD; }
        else          { re = att_real + (size_t)(idx - BQ) * FD; im = att_imag + (size_t)(idx - BQ) * FD; }
        float2 vr = *(const float2*)(re + f);
        float2 vi = *(const float2*)(im + f);
        float s0 = vr.x * vr.x + vi.x * vi.x;
        if (s0 > 0.0f) {
            float iv = frsq(s0);
            sr0 += s0 * iv; sc0 += vr.x * iv; ss0 += vi.x * iv;
        } else sc0 += 1.0f;                     // atan2(0,0)=0
        float s1 = vr.y * vr.y + vi.y * vi.y;
        if (s1 > 0.0f) {
            float iv = frsq(s1);
            sr1 += s1 * iv; sc1 += vr.y * iv; ss1 += vi.y * iv;
        } else sc1 += 1.0f;
    }
    const float inv = 1.0f / KTOP;
    float mr0 = sr0 * inv + EPSF, mc0 = sc0 * inv, ms0 = ss0 * inv;
    float mr1 = sr1 * inv + EPSF, mc1 = sc1 * inv, ms1 = ss1 * inv;
    float q0 = mc0 * mc0 + ms0 * ms0;
    float q1 = mc1 * mc1 + ms1 * ms1;
    float i0 = (q0 > 0.0f) ? frsq(q0) : 0.0f;   // q==0 -> phi=atan2(0,0)=0 -> cos=1,sin=0
    float i1 = (q1 > 0.0f) ? frsq(q1) : 0.0f;
    float c0 = (q0 > 0.0f) ? mc0 * i0 : 1.0f;
    float s0v = ms0 * i0;
    float c1 = (q1 > 0.0f) ? mc1 * i1 : 1.0f;
    float s1v = ms1 * i1;
    size_t obase = (size_t)b * FD + f;
    float2 xr = *(const float2*)(x_real + obase);
    float2 xi = *(const float2*)(x_imag + obase);
    float2 outr = make_float2((1.0f - a) * xr.x + a * (mr0 * c0),
                              (1.0f - a) * xr.y + a * (mr1 * c1));
    float2 outi = make_float2((1.0f - a) * xi.x + a * (mr0 * s0v),
                              (1.0f - a) * xi.y + a * (mr1 * s1v));
    *(float2*)(out + obase) = outr;
    *(float2*)(out + (size_t)BQ * FD + obase) = outi;
}

extern "C" void kernel_launch(void* const* d_in, const int* in_sizes, int n_in,
                              void* d_out, int out_size, void* d_ws, size_t ws_size,
                              hipStream_t stream) {
    const float* x_real   = (const float*)d_in[0];
    const float* x_imag   = (const float*)d_in[1];
    const float* att_real = (const float*)d_in[2];
    const float* att_imag = (const float*)d_in[3];
    const float* alpha    = (const float*)d_in[4];
    float* out = (float*)d_out;

    normalize_kernel<<<NDB, 256, 0, stream>>>(x_real, x_imag, att_real, att_imag);
    gemm_mfma<<<dim3(NDB / 128, BQ / 128), 256, 0, stream>>>();
    topk_agg_kernel<<<BQ, 256, 0, stream>>>(x_real, x_imag, att_real, att_imag, alpha, out);
}